// Round 2
// baseline (739.869 us; speedup 1.0000x reference)
//
#include <hip/hip_runtime.h>
#include <hip/hip_bf16.h>

typedef short s16x8 __attribute__((ext_vector_type(8)));
typedef unsigned short u16x4 __attribute__((ext_vector_type(4)));
typedef float f32x4 __attribute__((ext_vector_type(4)));
typedef unsigned short u16;

#define DEV static __device__ __forceinline__

#if __has_builtin(__builtin_amdgcn_exp2f)
#define EXP2F(x) __builtin_amdgcn_exp2f(x)
#else
#define EXP2F(x) exp2f(x)
#endif

constexpr int D    = 256;
constexpr int SEQ  = 4096;
constexpr int NB   = 8;
constexpr int NTOK = NB * SEQ;                 // 32768
constexpr size_t N_EMB = (size_t)NTOK * D;     // 8388608 elems
constexpr size_t N_W   = (size_t)D * D;        // 65536 elems
// softmax scale folded into exp2: (1/sqrt(256)) * log2(e)
constexpr float SM_C = 0.09016844005556021f;

DEV u16 f2bf(float f){ unsigned v; __builtin_memcpy(&v,&f,4); v += 0x7fffu + ((v>>16)&1u); return (u16)(v>>16); }

DEV float rmax16(float v){
  v = fmaxf(v, __shfl_xor(v,1)); v = fmaxf(v, __shfl_xor(v,2));
  v = fmaxf(v, __shfl_xor(v,4)); v = fmaxf(v, __shfl_xor(v,8));
  return v;
}
DEV float rsum16(float v){
  v += __shfl_xor(v,1); v += __shfl_xor(v,2);
  v += __shfl_xor(v,4); v += __shfl_xor(v,8);
  return v;
}

// ---------------------------------------------------------------------------
// Kernel 0: f32 -> bf16 (RNE) convert of TE, SE, Wq, Wk, Wv into workspace.
// dst layout: TEb | SEb | Wqb | Wkb | Wvb (contiguous bf16).
// ---------------------------------------------------------------------------
__global__ __launch_bounds__(256)
void cvt_all(const float* __restrict__ TE, const float* __restrict__ SE,
             const float* __restrict__ Wq, const float* __restrict__ Wk,
             const float* __restrict__ Wv, u16* __restrict__ dst)
{
  const size_t total4 = (2*N_EMB + 3*N_W) / 4;
  for (size_t i = (size_t)blockIdx.x*256 + threadIdx.x; i < total4;
       i += (size_t)gridDim.x*256) {
    size_t e = i*4;
    const float* s;
    if      (e < N_EMB)            s = TE + e;
    else if (e < 2*N_EMB)          s = SE + (e - N_EMB);
    else if (e < 2*N_EMB + N_W)    s = Wq + (e - 2*N_EMB);
    else if (e < 2*N_EMB + 2*N_W)  s = Wk + (e - 2*N_EMB - N_W);
    else                           s = Wv + (e - 2*N_EMB - 2*N_W);
    f32x4 v = *(const f32x4*)s;
    u16x4 o;
#pragma unroll
    for (int j = 0; j < 4; j++) o[j] = f2bf(v[j]);
    *(u16x4*)(dst + e) = o;
  }
}

// ---------------------------------------------------------------------------
// Kernel 1: QKV projections (bf16 in/out). mode 0: Q = TE@Wq^T+bq (row-major)
//           mode 1: K = SE@Wk^T+bk (row-major), mode 2: V^T [b][o][s]
// ---------------------------------------------------------------------------
__global__ __launch_bounds__(256, 2)
void qkv_proj(const u16* __restrict__ TEb, const u16* __restrict__ SEb,
              const u16* __restrict__ Wqb, const float* __restrict__ bq,
              const u16* __restrict__ Wkb, const float* __restrict__ bk,
              const u16* __restrict__ Wvb, const float* __restrict__ bv,
              u16* __restrict__ Qb, u16* __restrict__ Kb, u16* __restrict__ Vt)
{
  const int mode = blockIdx.y;
  const int t0   = blockIdx.x * 64;
  const int lane = threadIdx.x & 63;
  const int wv   = threadIdx.x >> 6;
  const int li   = lane & 15, grp = lane >> 4;

  const u16*   X    = (mode == 0) ? TEb : SEb;
  const u16*   W    = (mode == 0) ? Wqb : (mode == 1) ? Wkb : Wvb;
  const float* bias = (mode == 0) ? bq  : (mode == 1) ? bk  : bv;

  if (mode < 2) {
    u16* Y = (mode == 0) ? Qb : Kb;
    const u16* xrow = X + (size_t)(t0 + 16*wv + li) * D + grp*8;
    s16x8 a[8];
#pragma unroll
    for (int ks = 0; ks < 8; ks++) a[ks] = *(const s16x8*)(xrow + ks*32);
    f32x4 acc[16];
#pragma unroll
    for (int i = 0; i < 16; i++) acc[i] = (f32x4){0.f,0.f,0.f,0.f};
#pragma unroll
    for (int nt = 0; nt < 16; nt++) {
      const u16* wrow = W + (size_t)(16*nt + li) * D + grp*8;
#pragma unroll
      for (int ks = 0; ks < 8; ks++) {
        s16x8 bf = *(const s16x8*)(wrow + ks*32);
        acc[nt] = __builtin_amdgcn_mfma_f32_16x16x32_bf16(a[ks], bf, acc[nt], 0,0,0);
      }
    }
#pragma unroll
    for (int nt = 0; nt < 16; nt++) {
      int col = li + 16*nt;
      float bb = bias[col];
#pragma unroll
      for (int r = 0; r < 4; r++) {
        int row = t0 + 16*wv + grp*4 + r;
        Y[(size_t)row*D + col] = f2bf(acc[nt][r] + bb);
      }
    }
  } else {
    // V^T: D[o][token] = Wv[o][:] . SE[token][:]; wave wv owns o in [64wv,+64)
    f32x4 acc[16];
#pragma unroll
    for (int i = 0; i < 16; i++) acc[i] = (f32x4){0.f,0.f,0.f,0.f};
#pragma unroll
    for (int ks = 0; ks < 8; ks++) {
      s16x8 a[4], bb[4];
#pragma unroll
      for (int mt = 0; mt < 4; mt++)
        a[mt] = *(const s16x8*)(W + (size_t)(64*wv + 16*mt + li) * D + ks*32 + grp*8);
#pragma unroll
      for (int nt = 0; nt < 4; nt++)
        bb[nt] = *(const s16x8*)(X + (size_t)(t0 + 16*nt + li) * D + ks*32 + grp*8);
#pragma unroll
      for (int mt = 0; mt < 4; mt++)
#pragma unroll
        for (int nt = 0; nt < 4; nt++)
          acc[mt*4+nt] = __builtin_amdgcn_mfma_f32_16x16x32_bf16(a[mt], bb[nt], acc[mt*4+nt], 0,0,0);
    }
    const int b = t0 >> 12, s0 = t0 & (SEQ - 1);
#pragma unroll
    for (int mt = 0; mt < 4; mt++) {
#pragma unroll
      for (int r = 0; r < 4; r++) {
        int o = 64*wv + 16*mt + grp*4 + r;
        float bb = bias[o];
        u16* yrow = Vt + ((size_t)b * D + o) * SEQ + s0;
#pragma unroll
        for (int nt = 0; nt < 4; nt++)
          yrow[16*nt + li] = f2bf(acc[mt*4+nt][r] + bb);
      }
    }
  }
}

// ---------------------------------------------------------------------------
// Kernel 2: flash attention + residual + LayerNorm, fused.
// Block = (batch b, 64-row q tile). 4 waves.
//   QK^T: wave wv owns q rows [16wv,+16) (Q frags in regs), K tile in LDS.
//   PV:   wave wv owns d cols [64wv,+64); P and alpha shared via LDS.
// ---------------------------------------------------------------------------
constexpr int KS_OFF = 0;        // K tile   32x256 bf16, 16B-chunk xor swizzle
constexpr int VT_OFF = 16384;    // V^T tile 256x32 bf16, xor swizzle
constexpr int P_OFF  = 32768;    // P 64x32 bf16 (epilogue: LN partials)
constexpr int AL_OFF = 36864;    // alpha f32[64]
constexpr int L_OFF  = 37120;    // l     f32[64]
constexpr int G_OFF  = 37376;    // gamma f32[256]
constexpr int BE_OFF = 38400;    // beta  f32[256]
constexpr int LDS_BYTES = 39424;

__global__ __launch_bounds__(256, 2)
void attn_ln(const u16* __restrict__ Qb, const u16* __restrict__ Kb,
             const u16* __restrict__ Vt, const float* __restrict__ TE,
             const float* __restrict__ gamma, const float* __restrict__ beta,
             float* __restrict__ out)
{
  __shared__ __align__(16) char smem[LDS_BYTES];
  const int tid  = threadIdx.x;
  const int lane = tid & 63, wv = tid >> 6;
  const int li   = lane & 15, grp = lane >> 4;
  const int b  = blockIdx.x & 7;                 // XCD swizzle: batch -> XCD
  const int q0 = (blockIdx.x >> 3) * 64;

  float* gam = (float*)(smem + G_OFF);
  float* bet = (float*)(smem + BE_OFF);
  gam[tid] = gamma[tid];
  bet[tid] = beta[tid];

  // Q fragments in registers: A[m=li][k], m-tile = wave's q strip
  const u16* qrow = Qb + ((size_t)b*SEQ + q0 + 16*wv + li) * D + grp*8;
  s16x8 qf[8];
#pragma unroll
  for (int ks = 0; ks < 8; ks++) qf[ks] = *(const s16x8*)(qrow + ks*32);

  f32x4 oacc[16];
#pragma unroll
  for (int i = 0; i < 16; i++) oacc[i] = (f32x4){0.f,0.f,0.f,0.f};
  float m_r[4] = {-1e30f,-1e30f,-1e30f,-1e30f};
  float l_r[4] = {0.f,0.f,0.f,0.f};

  const u16* Kbase = Kb + (size_t)b * SEQ * D;
  const u16* Vbase = Vt + (size_t)b * D * SEQ;
  float* alpha_lds = (float*)(smem + AL_OFF);
  u16*   Pl        = (u16*)(smem + P_OFF);

  for (int kt = 0; kt < SEQ/32; kt++) {
    const int k0 = kt * 32;
    __syncthreads();   // protect K/Vt overwrite vs previous iter's reads
    {
      const u16* kg = Kbase + (size_t)k0 * D;
#pragma unroll
      for (int c = 0; c < 4; c++) {
        int g = tid + 256*c;
        int r = g >> 5, jj = g & 31;
        *(s16x8*)(smem + KS_OFF + r*512 + 16*(jj ^ (r & 7))) = *(const s16x8*)(kg + g*8);
      }
      const u16* vg = Vbase + (size_t)tid * SEQ + k0;
#pragma unroll
      for (int j = 0; j < 4; j++)
        *(s16x8*)(smem + VT_OFF + tid*64 + 16*(j ^ (tid & 3) ^ ((tid >> 2) & 3))) =
            *(const s16x8*)(vg + j*8);
    }
    __syncthreads();

    // S = Q K^T for this wave's 16 q rows x 32 k cols
    f32x4 sa0 = {0.f,0.f,0.f,0.f}, sa1 = {0.f,0.f,0.f,0.f};
    {
      const int r0 = li, r1 = li + 16;
      const char* kb0 = smem + KS_OFF + r0*512;
      const char* kb1 = smem + KS_OFF + r1*512;
#pragma unroll
      for (int ks = 0; ks < 8; ks++) {
        s16x8 k0f = *(const s16x8*)(kb0 + 16*((4*ks + grp) ^ (r0 & 7)));
        sa0 = __builtin_amdgcn_mfma_f32_16x16x32_bf16(qf[ks], k0f, sa0, 0,0,0);
        s16x8 k1f = *(const s16x8*)(kb1 + 16*((4*ks + grp) ^ (r1 & 7)));
        sa1 = __builtin_amdgcn_mfma_f32_16x16x32_bf16(qf[ks], k1f, sa1, 0,0,0);
      }
    }

    // online softmax (rows q = 16wv + 4grp + r, stats across 16 li-lanes)
#pragma unroll
    for (int r = 0; r < 4; r++) {
      float tmax = rmax16(fmaxf(sa0[r], sa1[r]));
      float mn = fmaxf(m_r[r], tmax);
      float al = EXP2F((m_r[r] - mn) * SM_C);
      float p0 = EXP2F((sa0[r] - mn) * SM_C);
      float p1 = EXP2F((sa1[r] - mn) * SM_C);
      float rs = rsum16(p0 + p1);
      l_r[r] = l_r[r] * al + rs;
      m_r[r] = mn;
      int row = 16*wv + grp*4 + r;
      Pl[row*32 + li]      = f2bf(p0);
      Pl[row*32 + li + 16] = f2bf(p1);
      if (li == 0) alpha_lds[row] = al;
    }
    __syncthreads();

    // rescale O (skip when no row max moved)
    float av[4][4];
    bool need = false;
#pragma unroll
    for (int mt = 0; mt < 4; mt++)
#pragma unroll
      for (int r = 0; r < 4; r++) {
        av[mt][r] = alpha_lds[16*mt + grp*4 + r];
        need |= (av[mt][r] < 1.0f);
      }
    if (__any(need)) {
#pragma unroll
      for (int mt = 0; mt < 4; mt++)
#pragma unroll
        for (int nt = 0; nt < 4; nt++)
#pragma unroll
          for (int r = 0; r < 4; r++)
            oacc[mt*4+nt][r] *= av[mt][r];
    }

    // O += P·V  (wave wv's d strip; V frags reused over 4 m-tiles)
    s16x8 vf[4];
#pragma unroll
    for (int nt = 0; nt < 4; nt++) {
      int d_ = 64*wv + 16*nt + li;
      vf[nt] = *(const s16x8*)(smem + VT_OFF + d_*64 + 16*(grp ^ (d_ & 3) ^ ((d_ >> 2) & 3)));
    }
#pragma unroll
    for (int mt = 0; mt < 4; mt++) {
      s16x8 pf = *(const s16x8*)(smem + P_OFF + (16*mt + li)*64 + grp*16);
#pragma unroll
      for (int nt = 0; nt < 4; nt++)
        oacc[mt*4+nt] = __builtin_amdgcn_mfma_f32_16x16x32_bf16(pf, vf[nt], oacc[mt*4+nt], 0,0,0);
    }
  }

  // ------------- epilogue: /l, +residual (f32), LayerNorm, f32 store -------------
  float* l_lds = (float*)(smem + L_OFF);
  if (li == 0) {
#pragma unroll
    for (int r = 0; r < 4; r++) l_lds[16*wv + grp*4 + r] = l_r[r];
  }
  __syncthreads();

  const float* Tg = TE + ((size_t)b*SEQ + q0) * D;
  float s1[4][4], s2[4][4];
#pragma unroll
  for (int mt = 0; mt < 4; mt++) {
#pragma unroll
    for (int r = 0; r < 4; r++) {
      int row = 16*mt + grp*4 + r;
      float linv = 1.0f / l_lds[row];
      float ps = 0.f, pq = 0.f;
#pragma unroll
      for (int nt = 0; nt < 4; nt++) {
        int d_ = 64*wv + 16*nt + li;
        float x = oacc[mt*4+nt][r] * linv + Tg[(size_t)row*D + d_];
        oacc[mt*4+nt][r] = x;
        ps += x; pq += x * x;
      }
      s1[mt][r] = rsum16(ps);
      s2[mt][r] = rsum16(pq);
    }
  }
  float* part1 = (float*)(smem + P_OFF);         // [64][4] per-wave partials
  float* part2 = (float*)(smem + P_OFF + 1024);
  if (li == 0) {
#pragma unroll
    for (int mt = 0; mt < 4; mt++)
#pragma unroll
      for (int r = 0; r < 4; r++) {
        int row = 16*mt + grp*4 + r;
        part1[row*4 + wv] = s1[mt][r];
        part2[row*4 + wv] = s2[mt][r];
      }
  }
  __syncthreads();
#pragma unroll
  for (int mt = 0; mt < 4; mt++) {
#pragma unroll
    for (int r = 0; r < 4; r++) {
      int row = 16*mt + grp*4 + r;
      float su = part1[row*4+0] + part1[row*4+1] + part1[row*4+2] + part1[row*4+3];
      float sq = part2[row*4+0] + part2[row*4+1] + part2[row*4+2] + part2[row*4+3];
      float mu  = su * (1.0f/256.0f);
      float var = sq * (1.0f/256.0f) - mu*mu;
      float rstd = rsqrtf(var + 1e-5f);
      float* orow = out + ((size_t)b*SEQ + q0 + row) * D;
#pragma unroll
      for (int nt = 0; nt < 4; nt++) {
        int d_ = 64*wv + 16*nt + li;
        orow[d_] = (oacc[mt*4+nt][r] - mu) * rstd * gam[d_] + bet[d_];
      }
    }
  }
}

// ---------------------------------------------------------------------------
extern "C" void kernel_launch(void* const* d_in, const int* in_sizes, int n_in,
                              void* d_out, int out_size, void* d_ws, size_t ws_size,
                              hipStream_t stream)
{
  (void)in_sizes; (void)n_in; (void)out_size; (void)ws_size;
  const float* SE = (const float*)d_in[0];
  const float* TE = (const float*)d_in[1];
  const float* Wq = (const float*)d_in[2];
  const float* bq = (const float*)d_in[3];
  const float* Wk = (const float*)d_in[4];
  const float* bk = (const float*)d_in[5];
  const float* Wv = (const float*)d_in[6];
  const float* bv = (const float*)d_in[7];
  const float* gm = (const float*)d_in[8];
  const float* bt = (const float*)d_in[9];

  u16* Qb  = (u16*)d_ws;              // [32768][256] bf16
  u16* Kb  = Qb + N_EMB;              // [32768][256] bf16
  u16* Vtr = Kb + N_EMB;              // [8][256][4096] bf16 (V transposed)
  u16* CVT = Vtr + N_EMB;             // TEb | SEb | Wqb | Wkb | Wvb
  u16* TEb = CVT;
  u16* SEb = TEb + N_EMB;
  u16* Wqb = SEb + N_EMB;
  u16* Wkb = Wqb + N_W;
  u16* Wvb = Wkb + N_W;

  cvt_all<<<2048, 256, 0, stream>>>(TE, SE, Wq, Wk, Wv, CVT);
  qkv_proj<<<dim3(NTOK/64, 3), 256, 0, stream>>>(TEb, SEb, Wqb, bq, Wkb, bk, Wvb, bv, Qb, Kb, Vtr);
  attn_ln<<<dim3((SEQ/64) * NB), 256, 0, stream>>>(Qb, Kb, Vtr, TE, gm, bt, (float*)d_out);
}